// Round 1
// baseline (1823.186 us; speedup 1.0000x reference)
//
#include <hip/hip_runtime.h>
#include <math.h>

#define MASK_FILL_F (-987654321.0f)

constexpr int Bb    = 64;
constexpr int Ntok  = 197;
constexpr int Dim   = 768;
constexpr int Heads = 12;
constexpr int Dh    = 64;
constexpr int Nqkv  = 3 * Dim;          // 2304
constexpr int Rows  = Bb * Ntok;        // 12608 (= 64*197, divisible by 64)

// ---------------------------------------------------------------------------
// Tiled fp32 GEMM, 64x64 tile, 256 threads, 4x4 microtile.
// ROTARY: epilogue applies rotary embedding to q/k regions (GEMM1).
// BIAS:   epilogue adds bias (GEMM2).
// M is implicit via gridDim.y*64; all dims here divide the tile sizes exactly.
// ---------------------------------------------------------------------------
template<bool ROTARY, bool BIAS>
__global__ __launch_bounds__(256) void gemm64(
    const float* __restrict__ A, const float* __restrict__ Bm,
    float* __restrict__ C, int K, int Nn,
    const float* __restrict__ pe, const float* __restrict__ bias)
{
  __shared__ float As[64][20];   // stride 20 floats = 80B: float4-aligned, 2-way-max banks
  __shared__ float Bs[16][68];   // stride 68 floats = 272B: float4-aligned

  const int tid = threadIdx.x;
  const int tx  = tid & 15, ty = tid >> 4;
  const int m0  = blockIdx.y * 64, n0 = blockIdx.x * 64;

  const int ar = tid >> 2, ac = (tid & 3) * 4;   // A-tile load: 64 rows x 16 cols
  const int br = tid >> 4, bc = (tid & 15) * 4;  // B-tile load: 16 rows x 64 cols

  float acc[4][4] = {};

  for (int k0 = 0; k0 < K; k0 += 16) {
    float4 av = *(const float4*)&A[(size_t)(m0 + ar) * K + k0 + ac];
    float4 bv = *(const float4*)&Bm[(size_t)(k0 + br) * Nn + n0 + bc];
    *(float4*)&As[ar][ac] = av;
    *(float4*)&Bs[br][bc] = bv;
    __syncthreads();
#pragma unroll
    for (int kk = 0; kk < 16; ++kk) {
      float a0 = As[ty * 4 + 0][kk];
      float a1 = As[ty * 4 + 1][kk];
      float a2 = As[ty * 4 + 2][kk];
      float a3 = As[ty * 4 + 3][kk];
      float b0 = Bs[kk][tx * 4 + 0];
      float b1 = Bs[kk][tx * 4 + 1];
      float b2 = Bs[kk][tx * 4 + 2];
      float b3 = Bs[kk][tx * 4 + 3];
      acc[0][0] += a0 * b0; acc[0][1] += a0 * b1; acc[0][2] += a0 * b2; acc[0][3] += a0 * b3;
      acc[1][0] += a1 * b0; acc[1][1] += a1 * b1; acc[1][2] += a1 * b2; acc[1][3] += a1 * b3;
      acc[2][0] += a2 * b0; acc[2][1] += a2 * b1; acc[2][2] += a2 * b2; acc[2][3] += a2 * b3;
      acc[3][0] += a3 * b0; acc[3][1] += a3 * b1; acc[3][2] += a3 * b2; acc[3][3] += a3 * b3;
    }
    __syncthreads();
  }

  // Epilogue. Columns of this thread: n0 + 4*tx + {0..3}; 64-wide tile lies in
  // exactly one of the q/k/v 768-wide regions (768 % 64 == 0).
  const bool do_rot = ROTARY && (n0 < 2 * Dim);   // q or k region only
  const int  dbase  = 4 * tx;                     // d = c % 64 since n0 % 64 == 0

#pragma unroll
  for (int ri = 0; ri < 4; ++ri) {
    const int row = m0 + ty * 4 + ri;
    float v0 = acc[ri][0], v1 = acc[ri][1], v2 = acc[ri][2], v3 = acc[ri][3];
    if (do_rot) {
      const int i = row % Ntok;
      const float* pr = pe + (size_t)i * Dh;
      // pair 0: d = dbase, dbase+1 -> m = dbase/2 ; pair 1 -> m+1
      const int m = dbase >> 1;
      float s0 = pr[m],     c0 = pr[32 + m];
      float s1 = pr[m + 1], c1 = pr[32 + m + 1];
      float n0v = v0 * c0 - v1 * s0;
      float n1v = v1 * c0 + v0 * s0;
      float n2v = v2 * c1 - v3 * s1;
      float n3v = v3 * c1 + v2 * s1;
      v0 = n0v; v1 = n1v; v2 = n2v; v3 = n3v;
    }
    if (BIAS) {
      const int c = n0 + 4 * tx;
      v0 += bias[c]; v1 += bias[c + 1]; v2 += bias[c + 2]; v3 += bias[c + 3];
    }
    float4 r = make_float4(v0, v1, v2, v3);
    *(float4*)&C[(size_t)row * Nn + n0 + 4 * tx] = r;
  }
}

// ---------------------------------------------------------------------------
// Attention: one block (256 thr = 4 waves) per (b,h). K,V staged in LDS.
// Per query row (one wave): scores via shfl-broadcast q, shuffle softmax,
// P*V with lane-per-d output. All fp32.
// ---------------------------------------------------------------------------
__global__ __launch_bounds__(256) void attn_kernel(
    const float* __restrict__ qkv, const float* __restrict__ scale,
    float* __restrict__ out)
{
  __shared__ float ks[Ntok * 65];   // stride 65: lane-over-j reads are 2-way max
  __shared__ float vs[Ntok * 64];   // stride 64: lane-over-d reads are 2-way max

  const int bh = blockIdx.x;
  const int b  = bh / Heads, h = bh % Heads;
  const float sc = scale[h];

  const int tid  = threadIdx.x;
  const int lane = tid & 63, wave = tid >> 6;
  const size_t base = (size_t)b * Ntok;

  // stage K and V (coalesced global reads, conflict-free LDS writes)
  for (int idx = tid; idx < Ntok * 64; idx += 256) {
    const int j = idx >> 6, d = idx & 63;
    ks[j * 65 + d] = qkv[(base + j) * Nqkv + Dim     + h * Dh + d];
    vs[j * 64 + d] = qkv[(base + j) * Nqkv + 2 * Dim + h * Dh + d];
  }
  __syncthreads();

  const int j3 = (lane < 5) ? (192 + lane) : 196;  // clamp to stay in-bounds

  for (int i = wave; i < Ntok; i += 4) {
    const float qv = qkv[(base + i) * Nqkv + h * Dh + lane];
    float s0 = 0.f, s1 = 0.f, s2 = 0.f, s3 = 0.f;
#pragma unroll 16
    for (int d = 0; d < 64; ++d) {
      const float qd = __shfl(qv, d, 64);
      s0 += qd * ks[(lane      ) * 65 + d];
      s1 += qd * ks[(lane +  64) * 65 + d];
      s2 += qd * ks[(lane + 128) * 65 + d];
      s3 += qd * ks[j3 * 65 + d];
    }
    s0 *= sc; s1 *= sc; s2 *= sc; s3 *= sc;
    if (lane       == i) s0 = MASK_FILL_F;
    if (lane +  64 == i) s1 = MASK_FILL_F;
    if (lane + 128 == i) s2 = MASK_FILL_F;
    if (lane + 192 == i) s3 = MASK_FILL_F;
    if (lane >= 5)       s3 = -1e30f;     // j out of range

    float mx = fmaxf(fmaxf(s0, s1), fmaxf(s2, s3));
#pragma unroll
    for (int off = 32; off; off >>= 1) mx = fmaxf(mx, __shfl_xor(mx, off, 64));

    float p0 = expf(s0 - mx), p1 = expf(s1 - mx), p2 = expf(s2 - mx), p3 = expf(s3 - mx);
    float sum = p0 + p1 + p2 + p3;
#pragma unroll
    for (int off = 32; off; off >>= 1) sum += __shfl_xor(sum, off, 64);
    const float r = 1.0f / sum;
    p0 *= r; p1 *= r; p2 *= r; p3 *= r;

    float o = 0.f;
#pragma unroll 8
    for (int jj = 0; jj < 64; ++jj) o += __shfl(p0, jj, 64) * vs[(jj      ) * 64 + lane];
#pragma unroll 8
    for (int jj = 0; jj < 64; ++jj) o += __shfl(p1, jj, 64) * vs[(64 + jj ) * 64 + lane];
#pragma unroll 8
    for (int jj = 0; jj < 64; ++jj) o += __shfl(p2, jj, 64) * vs[(128 + jj) * 64 + lane];
#pragma unroll
    for (int jj = 0; jj < 5;  ++jj) o += __shfl(p3, jj, 64) * vs[(192 + jj) * 64 + lane];

    out[(base + i) * Dim + h * Dh + lane] = o;
  }
}

// ---------------------------------------------------------------------------
extern "C" void kernel_launch(void* const* d_in, const int* in_sizes, int n_in,
                              void* d_out, int out_size, void* d_ws, size_t ws_size,
                              hipStream_t stream) {
  const float* x      = (const float*)d_in[0];  // [64,197,768]
  const float* pe     = (const float*)d_in[1];  // [1,197,64]
  const float* w_qkv  = (const float*)d_in[2];  // [768,2304]
  const float* scale  = (const float*)d_in[3];  // [12]
  const float* w_out  = (const float*)d_in[4];  // [768,768]
  const float* b_out  = (const float*)d_in[5];  // [768]
  float* out = (float*)d_out;                   // [64,197,768]

  float* qkv  = (float*)d_ws;                          // 12608*2304 floats (116 MB)
  float* attn = qkv + (size_t)Rows * Nqkv;             // 12608*768  floats (38.7 MB)

  dim3 blk(256);

  // GEMM1: qkv = x @ w_qkv, rotary fused into epilogue for q/k regions
  dim3 g1(Nqkv / 64, Rows / 64);   // 36 x 197
  gemm64<true, false><<<g1, blk, 0, stream>>>(x, w_qkv, qkv, Dim, Nqkv, pe, nullptr);

  // Attention: one block per (b,h)
  attn_kernel<<<Bb * Heads, blk, 0, stream>>>(qkv, scale, attn);

  // GEMM2: out = attn @ w_out + b_out
  dim3 g2(Dim / 64, Rows / 64);    // 12 x 197
  gemm64<false, true><<<g2, blk, 0, stream>>>(attn, w_out, out, Dim, Dim, nullptr, b_out);
}

// Round 2
// 564.788 us; speedup vs baseline: 3.2281x; 3.2281x over previous
//
#include <hip/hip_runtime.h>
#include <math.h>

#define MASK_FILL_F (-987654321.0f)

typedef unsigned short u16;
typedef unsigned int   u32;

constexpr int Bb   = 64;
constexpr int Ntok = 197;
constexpr int Dim  = 768;
constexpr int Heads= 12;
constexpr int Dh   = 64;
constexpr int Nq3  = 2304;      // 3*Dim
constexpr int Rows = 12608;     // 64*197
constexpr int Mpad = 12672;     // 99*128

using f32x4  = __attribute__((ext_vector_type(4))) float;
using bf16x8 = __attribute__((ext_vector_type(8))) short;   // 8 bf16 (4 VGPRs)

__device__ __forceinline__ u16 f2bf(float f) {          // RNE float->bf16
  u32 u = __float_as_uint(f);
  u = (u + 0x7fffu + ((u >> 16) & 1u)) >> 16;
  return (u16)u;
}

__device__ __forceinline__ void stage16(const void* gp, void* lp) {
  // async global->LDS, 16B/lane; LDS dest = uniform base + lane*16
  __builtin_amdgcn_global_load_lds(
      (const __attribute__((address_space(1))) u32*)gp,
      (__attribute__((address_space(3))) u32*)lp, 16, 0, 0);
}

// ---------------------------------------------------------------------------
// fp32 -> bf16 elementwise convert (x)
// ---------------------------------------------------------------------------
__global__ __launch_bounds__(256) void cvt_bf16(const float* __restrict__ in,
                                                u16* __restrict__ out, int n4) {
  const int i = blockIdx.x * 256 + threadIdx.x;
  if (i < n4) {
    const float4 v = *(const float4*)&in[(size_t)i * 4];
    ushort4 u;
    u.x = f2bf(v.x); u.y = f2bf(v.y); u.z = f2bf(v.z); u.w = f2bf(v.w);
    *(ushort4*)&out[(size_t)i * 4] = u;
  }
}

// ---------------------------------------------------------------------------
// fp32 [R][C] -> bf16 [C][R] transpose (weights)
// ---------------------------------------------------------------------------
__global__ __launch_bounds__(256) void transpose_cvt(const float* __restrict__ in,
                                                     u16* __restrict__ out,
                                                     int R, int C) {
  __shared__ float t[32][33];
  const int c0 = blockIdx.x * 32, r0 = blockIdx.y * 32;
  const int tx = threadIdx.x & 31, ty = threadIdx.x >> 5;
#pragma unroll
  for (int rr = ty; rr < 32; rr += 8)
    t[rr][tx] = in[(size_t)(r0 + rr) * C + c0 + tx];
  __syncthreads();
#pragma unroll
  for (int cc = ty; cc < 32; cc += 8)
    out[(size_t)(c0 + cc) * R + r0 + tx] = f2bf(t[tx][cc]);
}

// ---------------------------------------------------------------------------
// bf16 MFMA GEMM, m97-structure: 128x128 tile, BK=32, 256 thr (4 waves),
// each wave = 64x64 C via 4x4 frags of 16x16x32. A [M][K], B^T [N][K].
// MODE 0: rotary epilogue (q/k cols), bf16 C.  MODE 1: +bias, fp32 C, row guard.
// ---------------------------------------------------------------------------
template<int MODE>
__global__ __launch_bounds__(256) void gemm_bt(
    const u16* __restrict__ Ag, const u16* __restrict__ Bg,
    void* __restrict__ Cv, int K, int Nn,
    const float* __restrict__ pe, const float* __restrict__ bias)
{
  __shared__ u16 As[128 * 32];
  __shared__ u16 Bs[128 * 32];
  const int tid = threadIdx.x, lane = tid & 63, w = tid >> 6;
  const int m0 = blockIdx.y * 128, n0 = blockIdx.x * 128;
  const int wm = (w & 1) * 64, wn = (w >> 1) * 64;
  const int tx = lane & 15, qk = lane >> 4;
  const int rs = lane >> 2, cs = (lane & 3) * 8;   // staging lane -> (row,col8)

  f32x4 acc[4][4] = {};

  for (int k0 = 0; k0 < K; k0 += 32) {
#pragma unroll
    for (int t = 0; t < 2; ++t) {
      const int r0 = w * 16 + t * 64;              // 16 rows per instruction
      stage16(Ag + (size_t)(m0 + r0 + rs) * K + k0 + cs, &As[r0 * 32]);
      stage16(Bg + (size_t)(n0 + r0 + rs) * K + k0 + cs, &Bs[r0 * 32]);
    }
    __syncthreads();                                // drains vmcnt + barrier
    bf16x8 af[4], bf[4];
#pragma unroll
    for (int f = 0; f < 4; ++f) {
      af[f] = *(const bf16x8*)&As[(wm + f * 16 + tx) * 32 + qk * 8];
      bf[f] = *(const bf16x8*)&Bs[(wn + f * 16 + tx) * 32 + qk * 8];
    }
#pragma unroll
    for (int fm = 0; fm < 4; ++fm)
#pragma unroll
      for (int fn = 0; fn < 4; ++fn)
        acc[fm][fn] = __builtin_amdgcn_mfma_f32_16x16x32_bf16(
            af[fm], bf[fn], acc[fm][fn], 0, 0, 0);
    __syncthreads();
  }

  // Epilogue. C/D layout: col = lane&15, row = (lane>>4)*4 + reg.
  if (MODE == 0) {
    u16* C = (u16*)Cv;
    const bool dorot = (n0 < 2 * Dim);   // tile fully inside q/k region (768|128 tiles)
#pragma unroll
    for (int fm = 0; fm < 4; ++fm) {
      const int rbase = m0 + wm + fm * 16 + qk * 4;
      int iq[4];
#pragma unroll
      for (int r = 0; r < 4; ++r) iq[r] = (rbase + r) % Ntok;
#pragma unroll
      for (int fn = 0; fn < 4; ++fn) {
        const int col = n0 + wn + fn * 16 + tx;
        const int mm  = (col & 63) >> 1;
        const int odd = col & 1;                   // == lane parity
#pragma unroll
        for (int r = 0; r < 4; ++r) {
          float v = acc[fm][fn][r];
          float res = v;
          if (dorot) {
            const float other = __shfl_xor(v, 1, 64);     // col pair partner
            const float sn = pe[iq[r] * 64 + mm];
            const float c2 = pe[iq[r] * 64 + 32 + mm];
            res = odd ? (v * c2 + other * sn) : (v * c2 - other * sn);
          }
          C[(size_t)(rbase + r) * Nn + col] = f2bf(res);
        }
      }
    }
  } else {
    float* C = (float*)Cv;
#pragma unroll
    for (int fm = 0; fm < 4; ++fm) {
      const int rbase = m0 + wm + fm * 16 + qk * 4;
#pragma unroll
      for (int fn = 0; fn < 4; ++fn) {
        const int col = n0 + wn + fn * 16 + tx;
        const float bv = bias[col];
#pragma unroll
        for (int r = 0; r < 4; ++r) {
          const int row = rbase + r;
          if (row < Rows) C[(size_t)row * Nn + col] = acc[fm][fn][r] + bv;
        }
      }
    }
  }
}

// ---------------------------------------------------------------------------
// Flash-tiled attention, fp32 compute / bf16 io. Block = (i-tile 64 rows, bh).
// Thread (jl = tid&31, rg = tid>>5): 8 rows x 2 j (scores), 8 rows x 2 d (out).
// Online softmax; P round-trips LDS for the j-redistribution in PV.
// ---------------------------------------------------------------------------
__global__ __launch_bounds__(256) void attn2(
    const u16* __restrict__ qkvB, const float* __restrict__ scale,
    u16* __restrict__ outB)
{
  __shared__ float qs[64 * 66];
  __shared__ float ks[64 * 66];
  __shared__ float vs[64 * 66];
  __shared__ float ps[64 * 68];

  const int it = blockIdx.x, bh = blockIdx.y;
  const int b = bh / Heads, h = bh % Heads;
  const int i0 = it * 64;
  const float sc = scale[h];
  const int tid = threadIdx.x;
  const int jl = tid & 31, rg = tid >> 5;
  const size_t rowbase = (size_t)b * Ntok;

  // stage q-tile (pre-scaled). 64 rows x 64 bf16 = 512 x 16B chunks.
  for (int idx = tid; idx < 512; idx += 256) {
    const int r = idx >> 3, c = (idx & 7) * 8;
    const uint4 u = *(const uint4*)(qkvB + (rowbase + i0 + r) * (size_t)Nq3 + h * Dh + c);
    float* dst = &qs[r * 66 + c];
    dst[0] = __uint_as_float(u.x << 16) * sc;
    dst[1] = __uint_as_float(u.x & 0xffff0000u) * sc;
    dst[2] = __uint_as_float(u.y << 16) * sc;
    dst[3] = __uint_as_float(u.y & 0xffff0000u) * sc;
    dst[4] = __uint_as_float(u.z << 16) * sc;
    dst[5] = __uint_as_float(u.z & 0xffff0000u) * sc;
    dst[6] = __uint_as_float(u.w << 16) * sc;
    dst[7] = __uint_as_float(u.w & 0xffff0000u) * sc;
  }

  float m_i[8], l_i[8], o0[8], o1[8];
#pragma unroll
  for (int rr = 0; rr < 8; ++rr) { m_i[rr] = -3.0e38f; l_i[rr] = 0.f; o0[rr] = 0.f; o1[rr] = 0.f; }

  for (int jt = 0; jt < 4; ++jt) {
    const int j0 = jt * 64;
    __syncthreads();                 // previous tile's ks/vs reads done
    for (int idx = tid; idx < 512; idx += 256) {
      const int r = idx >> 3, c = (idx & 7) * 8;
      const size_t grow = (rowbase + j0 + r) * (size_t)Nq3;
      const uint4 uk = *(const uint4*)(qkvB + grow + Dim + h * Dh + c);
      const uint4 uv = *(const uint4*)(qkvB + grow + 2 * Dim + h * Dh + c);
      float* dk = &ks[r * 66 + c];
      float* dv = &vs[r * 66 + c];
      dk[0] = __uint_as_float(uk.x << 16); dk[1] = __uint_as_float(uk.x & 0xffff0000u);
      dk[2] = __uint_as_float(uk.y << 16); dk[3] = __uint_as_float(uk.y & 0xffff0000u);
      dk[4] = __uint_as_float(uk.z << 16); dk[5] = __uint_as_float(uk.z & 0xffff0000u);
      dk[6] = __uint_as_float(uk.w << 16); dk[7] = __uint_as_float(uk.w & 0xffff0000u);
      dv[0] = __uint_as_float(uv.x << 16); dv[1] = __uint_as_float(uv.x & 0xffff0000u);
      dv[2] = __uint_as_float(uv.y << 16); dv[3] = __uint_as_float(uv.y & 0xffff0000u);
      dv[4] = __uint_as_float(uv.z << 16); dv[5] = __uint_as_float(uv.z & 0xffff0000u);
      dv[6] = __uint_as_float(uv.w << 16); dv[7] = __uint_as_float(uv.w & 0xffff0000u);
    }
    __syncthreads();

    // scores: s[8 rows][2 j]
    float s[8][2];
#pragma unroll
    for (int rr = 0; rr < 8; ++rr) { s[rr][0] = 0.f; s[rr][1] = 0.f; }
#pragma unroll 4
    for (int d2 = 0; d2 < 32; ++d2) {
      const float2 k0v = *(const float2*)&ks[jl * 66 + d2 * 2];
      const float2 k1v = *(const float2*)&ks[(jl + 32) * 66 + d2 * 2];
#pragma unroll
      for (int rr = 0; rr < 8; ++rr) {
        const float2 qv = *(const float2*)&qs[(rg * 8 + rr) * 66 + d2 * 2];
        s[rr][0] += qv.x * k0v.x + qv.y * k0v.y;
        s[rr][1] += qv.x * k1v.x + qv.y * k1v.y;
      }
    }

    // mask + online softmax (reductions over the 32-lane j-group)
#pragma unroll
    for (int rr = 0; rr < 8; ++rr) {
      const int ig  = i0 + rg * 8 + rr;
      const int jg0 = j0 + jl, jg1 = j0 + jl + 32;
      if (jg0 >= Ntok) s[rr][0] = -1e30f; else if (jg0 == ig) s[rr][0] = MASK_FILL_F;
      if (jg1 >= Ntok) s[rr][1] = -1e30f; else if (jg1 == ig) s[rr][1] = MASK_FILL_F;
      float tm = fmaxf(s[rr][0], s[rr][1]);
#pragma unroll
      for (int off = 16; off; off >>= 1) tm = fmaxf(tm, __shfl_xor(tm, off, 32));
      const float mn = fmaxf(m_i[rr], tm);
      const float al = __expf(m_i[rr] - mn);
      const float p0 = __expf(s[rr][0] - mn);
      const float p1 = __expf(s[rr][1] - mn);
      float psum = p0 + p1;
#pragma unroll
      for (int off = 16; off; off >>= 1) psum += __shfl_xor(psum, off, 32);
      l_i[rr] = l_i[rr] * al + psum;
      m_i[rr] = mn;
      o0[rr] *= al; o1[rr] *= al;
      ps[(rg * 8 + rr) * 68 + jl]      = p0;   // intra-rgroup (same wave): no barrier
      ps[(rg * 8 + rr) * 68 + jl + 32] = p1;
    }

    // PV: o[rows][d = 2*jl, 2*jl+1] += sum_j p[i][j] * v[j][d]
#pragma unroll 4
    for (int j2 = 0; j2 < 32; ++j2) {
      const float2 v0 = *(const float2*)&vs[(2 * j2) * 66 + jl * 2];
      const float2 v1 = *(const float2*)&vs[(2 * j2 + 1) * 66 + jl * 2];
#pragma unroll
      for (int rr = 0; rr < 8; ++rr) {
        const float2 pv = *(const float2*)&ps[(rg * 8 + rr) * 68 + 2 * j2];
        o0[rr] += pv.x * v0.x + pv.y * v1.x;
        o1[rr] += pv.x * v0.y + pv.y * v1.y;
      }
    }
  }

#pragma unroll
  for (int rr = 0; rr < 8; ++rr) {
    const int ig = i0 + rg * 8 + rr;
    if (ig < Ntok) {
      const float rcp = 1.0f / l_i[rr];
      ushort2 u2;
      u2.x = f2bf(o0[rr] * rcp);
      u2.y = f2bf(o1[rr] * rcp);
      *(ushort2*)(outB + (rowbase + ig) * (size_t)Dim + h * Dh + jl * 2) = u2;
    }
  }
}

// ---------------------------------------------------------------------------
extern "C" void kernel_launch(void* const* d_in, const int* in_sizes, int n_in,
                              void* d_out, int out_size, void* d_ws, size_t ws_size,
                              hipStream_t stream) {
  const float* x     = (const float*)d_in[0];  // [64,197,768]
  const float* pe    = (const float*)d_in[1];  // [1,197,64]
  const float* w_qkv = (const float*)d_in[2];  // [768,2304]
  const float* scale = (const float*)d_in[3];  // [12]
  const float* w_out = (const float*)d_in[4];  // [768,768]
  const float* b_out = (const float*)d_in[5];  // [768]
  float* out = (float*)d_out;                  // [64,197,768] fp32

  u16* xb    = (u16*)d_ws;                       // [Mpad][768]
  u16* wqkvT = xb    + (size_t)Mpad * Dim;       // [2304][768]
  u16* woutT = wqkvT + (size_t)Nq3 * Dim;        // [768][768]
  u16* qkvB  = woutT + (size_t)Dim * Dim;        // [Mpad][2304]
  u16* attnB = qkvB  + (size_t)Mpad * Nq3;       // [Mpad][768]   total ~102 MB

  cvt_bf16<<<(Rows * Dim / 4 + 255) / 256, 256, 0, stream>>>(x, xb, Rows * Dim / 4);
  transpose_cvt<<<dim3(Nq3 / 32, Dim / 32), 256, 0, stream>>>(w_qkv, wqkvT, Dim, Nq3);
  transpose_cvt<<<dim3(Dim / 32, Dim / 32), 256, 0, stream>>>(w_out, woutT, Dim, Dim);

  gemm_bt<0><<<dim3(Nq3 / 128, Mpad / 128), 256, 0, stream>>>(
      xb, wqkvT, qkvB, Dim, Nq3, pe, nullptr);

  attn2<<<dim3(4, Bb * Heads), 256, 0, stream>>>(qkvB, scale, attnB);

  gemm_bt<1><<<dim3(Dim / 128, Mpad / 128), 256, 0, stream>>>(
      attnB, woutT, out, Dim, Dim, nullptr, b_out);
}

// Round 4
// 284.850 us; speedup vs baseline: 6.4005x; 1.9828x over previous
//
#include <hip/hip_runtime.h>
#include <math.h>

#define MASK_FILL_F (-987654321.0f)

typedef unsigned short u16;
typedef unsigned int   u32;

constexpr int Bb   = 64;
constexpr int Ntok = 197;
constexpr int Dim  = 768;
constexpr int Heads= 12;
constexpr int Dh   = 64;
constexpr int Nq3  = 2304;      // 3*Dim
constexpr int Rows = 12608;     // 64*197
constexpr int Mpad = 12672;     // 99*128

using f32x4  = __attribute__((ext_vector_type(4))) float;
using bf16x8 = __attribute__((ext_vector_type(8))) short;   // 8 bf16 (4 VGPRs)

__device__ __forceinline__ u16 f2bf(float f) {          // RNE float->bf16
  u32 u = __float_as_uint(f);
  u = (u + 0x7fffu + ((u >> 16) & 1u)) >> 16;
  return (u16)u;
}

__device__ __forceinline__ void stage16(const void* gp, void* lp) {
  __builtin_amdgcn_global_load_lds(
      (const __attribute__((address_space(1))) u32*)gp,
      (__attribute__((address_space(3))) u32*)lp, 16, 0, 0);
}

// ---------------------------------------------------------------------------
__global__ __launch_bounds__(256) void cvt_bf16(const float* __restrict__ in,
                                                u16* __restrict__ out, int n4) {
  const int i = blockIdx.x * 256 + threadIdx.x;
  if (i < n4) {
    const float4 v = *(const float4*)&in[(size_t)i * 4];
    ushort4 u;
    u.x = f2bf(v.x); u.y = f2bf(v.y); u.z = f2bf(v.z); u.w = f2bf(v.w);
    *(ushort4*)&out[(size_t)i * 4] = u;
  }
}

// ---------------------------------------------------------------------------
__global__ __launch_bounds__(256) void transpose_cvt(const float* __restrict__ in,
                                                     u16* __restrict__ out,
                                                     int R, int C) {
  __shared__ float t[32][33];
  const int c0 = blockIdx.x * 32, r0 = blockIdx.y * 32;
  const int tx = threadIdx.x & 31, ty = threadIdx.x >> 5;
#pragma unroll
  for (int rr = ty; rr < 32; rr += 8)
    t[rr][tx] = in[(size_t)(r0 + rr) * C + c0 + tx];
  __syncthreads();
#pragma unroll
  for (int cc = ty; cc < 32; cc += 8)
    out[(size_t)(c0 + cc) * R + r0 + tx] = f2bf(t[tx][cc]);
}

// ---------------------------------------------------------------------------
// bf16 MFMA GEMM (m97 structure), 128x128 tile, BK=32. A [M][K], B^T [N][K].
// MODE 0: rotary epilogue, bf16 C.  MODE 1: +bias, fp32 C, row guard.
// (verified passing in round 2 — unchanged)
// ---------------------------------------------------------------------------
template<int MODE>
__global__ __launch_bounds__(256) void gemm_bt(
    const u16* __restrict__ Ag, const u16* __restrict__ Bg,
    void* __restrict__ Cv, int K, int Nn,
    const float* __restrict__ pe, const float* __restrict__ bias)
{
  __shared__ u16 As[128 * 32];
  __shared__ u16 Bs[128 * 32];
  const int tid = threadIdx.x, lane = tid & 63, w = tid >> 6;
  const int m0 = blockIdx.y * 128, n0 = blockIdx.x * 128;
  const int wm = (w & 1) * 64, wn = (w >> 1) * 64;
  const int tx = lane & 15, qk = lane >> 4;
  const int rs = lane >> 2, cs = (lane & 3) * 8;

  f32x4 acc[4][4] = {};

  for (int k0 = 0; k0 < K; k0 += 32) {
#pragma unroll
    for (int t = 0; t < 2; ++t) {
      const int r0 = w * 16 + t * 64;
      stage16(Ag + (size_t)(m0 + r0 + rs) * K + k0 + cs, &As[r0 * 32]);
      stage16(Bg + (size_t)(n0 + r0 + rs) * K + k0 + cs, &Bs[r0 * 32]);
    }
    __syncthreads();
    bf16x8 af[4], bf[4];
#pragma unroll
    for (int f = 0; f < 4; ++f) {
      af[f] = *(const bf16x8*)&As[(wm + f * 16 + tx) * 32 + qk * 8];
      bf[f] = *(const bf16x8*)&Bs[(wn + f * 16 + tx) * 32 + qk * 8];
    }
#pragma unroll
    for (int fm = 0; fm < 4; ++fm)
#pragma unroll
      for (int fn = 0; fn < 4; ++fn)
        acc[fm][fn] = __builtin_amdgcn_mfma_f32_16x16x32_bf16(
            af[fm], bf[fn], acc[fm][fn], 0, 0, 0);
    __syncthreads();
  }

  if (MODE == 0) {
    u16* C = (u16*)Cv;
    const bool dorot = (n0 < 2 * Dim);
#pragma unroll
    for (int fm = 0; fm < 4; ++fm) {
      const int rbase = m0 + wm + fm * 16 + qk * 4;
      int iq[4];
#pragma unroll
      for (int r = 0; r < 4; ++r) iq[r] = (rbase + r) % Ntok;
#pragma unroll
      for (int fn = 0; fn < 4; ++fn) {
        const int col = n0 + wn + fn * 16 + tx;
        const int mm  = (col & 63) >> 1;
        const int odd = col & 1;
#pragma unroll
        for (int r = 0; r < 4; ++r) {
          float v = acc[fm][fn][r];
          float res = v;
          if (dorot) {
            const float other = __shfl_xor(v, 1, 64);
            const float sn = pe[iq[r] * 64 + mm];
            const float c2 = pe[iq[r] * 64 + 32 + mm];
            res = odd ? (v * c2 + other * sn) : (v * c2 - other * sn);
          }
          C[(size_t)(rbase + r) * Nn + col] = f2bf(res);
        }
      }
    }
  } else {
    float* C = (float*)Cv;
#pragma unroll
    for (int fm = 0; fm < 4; ++fm) {
      const int rbase = m0 + wm + fm * 16 + qk * 4;
#pragma unroll
      for (int fn = 0; fn < 4; ++fn) {
        const int col = n0 + wn + fn * 16 + tx;
        const float bv = bias[col];
#pragma unroll
        for (int r = 0; r < 4; ++r) {
          const int row = rbase + r;
          if (row < Rows) C[(size_t)row * Nn + col] = acc[fm][fn][r] + bv;
        }
      }
    }
  }
}

// ---------------------------------------------------------------------------
// MFMA flash attention v4. Block = (i-tile of 64, bh), 4 waves; wave w owns
// i-rows [16w, 16w+16).
//   S^T = K·Q^T   (both operands natural [token][d] LDS tiles, zero transposes)
//   softmax in S^T C-layout: row i = 16w + tx per lane, reduce over quads
//   P stays IN REGISTERS: lane (tx,q)'s 16 sT regs are exactly the 16 k-slots
//     of its PV A-operand, provided V^T columns are permuted to match:
//     vts col c <- V row 32*(c>>5) + 16*((c>>2)&1) + 4*((c>>3)&3) + (c&3).
//     (robust to the HW's internal reg-element->k-slot map: A and B use
//      identical indexing, so any permutation cancels.)
// LS = 72 u16 (144 B): 64 data + 8 pad. Round-3 bug was LS=40 < 64 -> rows
// overlapped and tiles self-corrupted. 3 tiles * 9216 B = 27.6 KB LDS.
// ---------------------------------------------------------------------------
constexpr int LS = 72;

__global__ __launch_bounds__(256) void attn4(
    const u16* __restrict__ qkvB, const float* __restrict__ scale,
    u16* __restrict__ outB)
{
  __shared__ u16 qs [64 * LS];   // Q  [i][d]
  __shared__ u16 ks [64 * LS];   // K  [j][d]
  __shared__ u16 vts[64 * LS];   // V^T[d][c], c = permuted j (see above)

  const int it = blockIdx.x, bh = blockIdx.y;
  const int b = bh / Heads, h = bh % Heads;
  const int i0 = it * 64;
  const float sc = scale[h];
  const int tid = threadIdx.x, lane = tid & 63, w = tid >> 6;
  const int tx = lane & 15, q = lane >> 4;
  const size_t rowbase = (size_t)b * Ntok;

  // ---- stage Q (natural [i][d]) ----
  for (int idx = tid; idx < 512; idx += 256) {
    const int r = idx >> 3, c8 = (idx & 7) * 8;
    *(uint4*)&qs[r * LS + c8] =
        *(const uint4*)(qkvB + (rowbase + i0 + r) * (size_t)Nq3 + h * Dh + c8);
  }

  float m_i = -3.0e38f, l_i = 0.f;     // per lane: row i = i0+16w+tx (dup x4 quads)
  f32x4 oacc[4] = {};                  // O[i=16w+4q+r][d=nb*16+tx]

  for (int jt = 0; jt < 4; ++jt) {
    const int j0 = jt * 64;
    __syncthreads();                   // prev tile's ks/vts reads done (covers qs @jt=0)

    // ---- stage K (natural [j][d]) ----
    for (int idx = tid; idx < 512; idx += 256) {
      const int r = idx >> 3, c8 = (idx & 7) * 8;
      *(uint4*)&ks[r * LS + c8] =
          *(const uint4*)(qkvB + (rowbase + j0 + r) * (size_t)Nq3 + Dim + h * Dh + c8);
    }
    // ---- stage V^T with permuted columns; zero cols whose j >= Ntok ----
    for (int idx = tid; idx < 512; idx += 256) {
      const int c = idx & 63, dc = (idx >> 6) * 8;
      const int jj = 32 * (c >> 5) + 16 * ((c >> 2) & 1) + 4 * ((c >> 3) & 3) + (c & 3);
      const bool valid = (j0 + jj) < Ntok;
      const uint4 u = *(const uint4*)(qkvB + (rowbase + j0 + jj) * (size_t)Nq3 +
                                      2 * Dim + h * Dh + dc);
      const u16* e = (const u16*)&u;
#pragma unroll
      for (int t2 = 0; t2 < 8; ++t2)
        vts[(dc + t2) * LS + c] = valid ? e[t2] : (u16)0;
    }
    __syncthreads();

    // ---- S^T = K·Q^T : sT[jb][r] = S[i = i0+16w+tx][j = j0+16jb+4q+r] ----
    f32x4 sT[4] = {};
#pragma unroll
    for (int kk = 0; kk < 2; ++kk) {
      const bf16x8 bq = *(const bf16x8*)&qs[(w * 16 + tx) * LS + kk * 32 + q * 8];
#pragma unroll
      for (int jb = 0; jb < 4; ++jb) {
        const bf16x8 ka = *(const bf16x8*)&ks[(jb * 16 + tx) * LS + kk * 32 + q * 8];
        sT[jb] = __builtin_amdgcn_mfma_f32_16x16x32_bf16(ka, bq, sT[jb], 0, 0, 0);
      }
    }

    // ---- scale + mask + online softmax (row i = i0+16w+tx) ----
    const int ig = i0 + 16 * w + tx;
    float mrow = -3.0e38f;
#pragma unroll
    for (int jb = 0; jb < 4; ++jb)
#pragma unroll
      for (int r = 0; r < 4; ++r) {
        const int jg = j0 + 16 * jb + 4 * q + r;
        float s = sT[jb][r] * sc;
        if (jg >= Ntok) s = -3.0e38f;
        else if (jg == ig) s = MASK_FILL_F;
        sT[jb][r] = s;
        mrow = fmaxf(mrow, s);
      }
    mrow = fmaxf(mrow, __shfl_xor(mrow, 16, 64));
    mrow = fmaxf(mrow, __shfl_xor(mrow, 32, 64));
    const float mnew  = fmaxf(m_i, mrow);
    const float alpha = __expf(m_i - mnew);
    m_i = mnew;

    // ---- P in registers, packed directly as the PV A-operand ----
    union { bf16x8 v; u16 e[8]; } pk[2];
    float lsum = 0.f;
#pragma unroll
    for (int jb = 0; jb < 4; ++jb)
#pragma unroll
      for (int r = 0; r < 4; ++r) {
        const float p = __expf(sT[jb][r] - mnew);
        lsum += p;
        pk[jb >> 1].e[(jb & 1) * 4 + r] = f2bf(p);
      }
    lsum += __shfl_xor(lsum, 16, 64);
    lsum += __shfl_xor(lsum, 32, 64);
    l_i = l_i * alpha + lsum;

    // rescale O accumulators: alpha for row 4q+r lives at lane 4q+r (quad 0)
#pragma unroll
    for (int r = 0; r < 4; ++r) {
      const float ar = __shfl(alpha, 4 * q + r, 64);
#pragma unroll
      for (int nb = 0; nb < 4; ++nb) oacc[nb][r] *= ar;
    }

    // ---- O += P·V : A = pk (registers), B^T = vts (permuted cols) ----
#pragma unroll
    for (int kk = 0; kk < 2; ++kk)
#pragma unroll
      for (int nb = 0; nb < 4; ++nb) {
        const bf16x8 vb = *(const bf16x8*)&vts[(nb * 16 + tx) * LS + kk * 32 + q * 8];
        oacc[nb] = __builtin_amdgcn_mfma_f32_16x16x32_bf16(pk[kk].v, vb, oacc[nb], 0, 0, 0);
      }
  }

  // ---- epilogue: divide by l, write bf16 ----
  const float linv = 1.0f / l_i;
#pragma unroll
  for (int r = 0; r < 4; ++r) {
    const float lr = __shfl(linv, 4 * q + r, 64);
    const int igr = i0 + 16 * w + 4 * q + r;
    if (igr < Ntok) {
#pragma unroll
      for (int nb = 0; nb < 4; ++nb)
        outB[(rowbase + igr) * (size_t)Dim + h * Dh + nb * 16 + tx] =
            f2bf(oacc[nb][r] * lr);
    }
  }
}

// ---------------------------------------------------------------------------
extern "C" void kernel_launch(void* const* d_in, const int* in_sizes, int n_in,
                              void* d_out, int out_size, void* d_ws, size_t ws_size,
                              hipStream_t stream) {
  const float* x     = (const float*)d_in[0];
  const float* pe    = (const float*)d_in[1];
  const float* w_qkv = (const float*)d_in[2];
  const float* scale = (const float*)d_in[3];
  const float* w_out = (const float*)d_in[4];
  const float* b_out = (const float*)d_in[5];
  float* out = (float*)d_out;

  u16* xb    = (u16*)d_ws;                       // [Mpad][768]
  u16* wqkvT = xb    + (size_t)Mpad * Dim;       // [2304][768]
  u16* woutT = wqkvT + (size_t)Nq3 * Dim;        // [768][768]
  u16* qkvB  = woutT + (size_t)Dim * Dim;        // [Mpad][2304]
  u16* attnB = qkvB  + (size_t)Mpad * Nq3;       // [Mpad][768]

  cvt_bf16<<<(Rows * Dim / 4 + 255) / 256, 256, 0, stream>>>(x, xb, Rows * Dim / 4);
  transpose_cvt<<<dim3(Nq3 / 32, Dim / 32), 256, 0, stream>>>(w_qkv, wqkvT, Dim, Nq3);
  transpose_cvt<<<dim3(Dim / 32, Dim / 32), 256, 0, stream>>>(w_out, woutT, Dim, Dim);

  gemm_bt<0><<<dim3(Nq3 / 128, Mpad / 128), 256, 0, stream>>>(
      xb, wqkvT, qkvB, Dim, Nq3, pe, nullptr);

  attn4<<<dim3(4, Bb * Heads), 256, 0, stream>>>(qkvB, scale, attnB);

  gemm_bt<1><<<dim3(Dim / 128, Mpad / 128), 256, 0, stream>>>(
      attnB, woutT, out, Dim, Dim, nullptr, b_out);
}